// Round 1
// baseline (6615.057 us; speedup 1.0000x reference)
//
#include <hip/hip_runtime.h>
#include <hip/hip_bf16.h>
#include <math.h>

#define SEQ_LEN 512
#define IN_SZ   4096
#define HID     2048
#define OUT_SZ  4096
#define G3      (3*HID)      // 6144
#define STEPS   30

// ---------------------------------------------------------------------------
// K0: Gi[t][r] = sum_k input[t][k] * enc_Wih[r][k] + enc_bih[r]
// A = input (512 x 4096), B = enc_Wih (6144 x 4096), both K-major (NT GEMM).
// 64x64 tile, BK=16, 256 threads, 4x4 microtile. fp32 (no fp32 MFMA on CDNA4).
// ---------------------------------------------------------------------------
#define BM 64
#define BN 64
#define BK 16
__global__ __launch_bounds__(256) void gemm_gi(
    const float* __restrict__ A, const float* __restrict__ B,
    const float* __restrict__ bias, float* __restrict__ C) {
  __shared__ float As[BK][BM];
  __shared__ float Bs[BK][BN];
  const int tid = threadIdx.x;
  const int m0 = blockIdx.x * BM;
  const int n0 = blockIdx.y * BN;
  const int tx = tid & 15, ty = tid >> 4;
  float acc[4][4] = {};
  for (int k0 = 0; k0 < IN_SZ; k0 += BK) {
#pragma unroll
    for (int i = 0; i < 4; i++) {
      int idx = tid + i * 256;
      int r = idx >> 4, k = idx & 15;
      As[k][r] = A[(size_t)(m0 + r) * IN_SZ + k0 + k];
      Bs[k][r] = B[(size_t)(n0 + r) * IN_SZ + k0 + k];
    }
    __syncthreads();
#pragma unroll
    for (int k = 0; k < BK; k++) {
      float a[4], b[4];
#pragma unroll
      for (int i = 0; i < 4; i++) { a[i] = As[k][ty * 4 + i]; b[i] = Bs[k][tx * 4 + i]; }
#pragma unroll
      for (int i = 0; i < 4; i++)
#pragma unroll
        for (int j = 0; j < 4; j++) acc[i][j] += a[i] * b[j];
    }
    __syncthreads();
  }
#pragma unroll
  for (int i = 0; i < 4; i++)
#pragma unroll
    for (int j = 0; j < 4; j++) {
      int m = m0 + ty * 4 + i, n = n0 + tx * 4 + j;
      C[(size_t)m * G3 + n] = acc[i][j] + bias[n];
    }
}

__device__ __forceinline__ float wave_reduce(float v) {
#pragma unroll
  for (int off = 32; off > 0; off >>= 1) v += __shfl_down(v, off, 64);
  return v;
}

// ---------------------------------------------------------------------------
// K1: one encoder GRU step. Block = 256 threads (4 waves), each wave owns one
// h-index j (3 gate rows j, j+H, j+2H of Whh). h_old staged in LDS.
// Grid = HID/4 = 512 blocks.
// ---------------------------------------------------------------------------
__global__ __launch_bounds__(256) void enc_step(
    const float* __restrict__ gi_row,   // Gi + t*G3 (bih already added)
    const float* __restrict__ h_old,
    const float* __restrict__ Whh,      // G3 x HID
    const float* __restrict__ bhh,
    float* __restrict__ h_new) {
  __shared__ float hsh[HID];
  const int tid = threadIdx.x;
#pragma unroll
  for (int i = 0; i < HID / 256; i++) hsh[tid + i * 256] = h_old[tid + i * 256];
  __syncthreads();
  const int wave = tid >> 6, lane = tid & 63;
  const int j = blockIdx.x * 4 + wave;
  const float4* hs4 = (const float4*)hsh;
  float dots[3];
#pragma unroll
  for (int g = 0; g < 3; g++) {
    const float4* wp = (const float4*)(Whh + (size_t)(g * HID + j) * HID);
    float acc = 0.f;
#pragma unroll
    for (int i = 0; i < 8; i++) {
      float4 w = wp[lane + i * 64];
      float4 h = hs4[lane + i * 64];
      acc += w.x * h.x + w.y * h.y + w.z * h.z + w.w * h.w;
    }
    dots[g] = wave_reduce(acc);
  }
  if (lane == 0) {
    float gr = dots[0] + bhh[j];
    float gz = dots[1] + bhh[j + HID];
    float gn = dots[2] + bhh[j + 2 * HID];
    float ir = gi_row[j], iz = gi_row[j + HID], in = gi_row[j + 2 * HID];
    float r = 1.f / (1.f + expf(-(ir + gr)));
    float z = 1.f / (1.f + expf(-(iz + gz)));
    float n = tanhf(in + r * gn);
    h_new[j] = (1.f - z) * n + z * hsh[j];
  }
}

// ---------------------------------------------------------------------------
// K2: one decoder GRU step. Same structure; gi = dec_Wih[:, idx] + dec_bih
// (x is one-hot), or just dec_bih on step 0 (x = zeros).
// ---------------------------------------------------------------------------
__global__ __launch_bounds__(256) void dec_step(
    const float* __restrict__ Wih,      // G3 x OUT_SZ
    const float* __restrict__ bih,
    const int* __restrict__ idxp, int has_idx,
    const float* __restrict__ h_old,
    const float* __restrict__ Whh,
    const float* __restrict__ bhh,
    float* __restrict__ h_new) {
  __shared__ float hsh[HID];
  const int tid = threadIdx.x;
#pragma unroll
  for (int i = 0; i < HID / 256; i++) hsh[tid + i * 256] = h_old[tid + i * 256];
  __syncthreads();
  const int wave = tid >> 6, lane = tid & 63;
  const int j = blockIdx.x * 4 + wave;
  const float4* hs4 = (const float4*)hsh;
  float dots[3];
#pragma unroll
  for (int g = 0; g < 3; g++) {
    const float4* wp = (const float4*)(Whh + (size_t)(g * HID + j) * HID);
    float acc = 0.f;
#pragma unroll
    for (int i = 0; i < 8; i++) {
      float4 w = wp[lane + i * 64];
      float4 h = hs4[lane + i * 64];
      acc += w.x * h.x + w.y * h.y + w.z * h.z + w.w * h.w;
    }
    dots[g] = wave_reduce(acc);
  }
  if (lane == 0) {
    int idx = has_idx ? *idxp : 0;
    float gi[3];
#pragma unroll
    for (int g = 0; g < 3; g++) {
      int row = g * HID + j;
      float v = bih[row];
      if (has_idx) v += Wih[(size_t)row * OUT_SZ + idx];
      gi[g] = v;
    }
    float gr = dots[0] + bhh[j];
    float gz = dots[1] + bhh[j + HID];
    float gn = dots[2] + bhh[j + 2 * HID];
    float r = 1.f / (1.f + expf(-(gi[0] + gr)));
    float z = 1.f / (1.f + expf(-(gi[1] + gz)));
    float n = tanhf(gi[2] + r * gn);
    h_new[j] = (1.f - z) * n + z * hsh[j];
  }
}

// ---------------------------------------------------------------------------
// K3: logits[r] = W_out[r,:] . h + b_out[r], wave per row, h in LDS.
// Grid = OUT_SZ/4 = 1024 blocks x 256 threads.
// ---------------------------------------------------------------------------
__global__ __launch_bounds__(256) void logits_kernel(
    const float* __restrict__ W, const float* __restrict__ b,
    const float* __restrict__ h, float* __restrict__ logits) {
  __shared__ float hsh[HID];
  const int tid = threadIdx.x;
#pragma unroll
  for (int i = 0; i < HID / 256; i++) hsh[tid + i * 256] = h[tid + i * 256];
  __syncthreads();
  const int wave = tid >> 6, lane = tid & 63;
  const int row = blockIdx.x * 4 + wave;
  const float4* hs4 = (const float4*)hsh;
  const float4* wp = (const float4*)(W + (size_t)row * HID);
  float acc = 0.f;
#pragma unroll
  for (int i = 0; i < 8; i++) {
    float4 w = wp[lane + i * 64];
    float4 hv = hs4[lane + i * 64];
    acc += w.x * hv.x + w.y * hv.y + w.z * hv.z + w.w * hv.w;
  }
  acc = wave_reduce(acc);
  if (lane == 0) logits[row] = acc + b[row];
}

// ---------------------------------------------------------------------------
// K4: single-block log_softmax over 4096 logits + argmax (lowest-index ties).
// ---------------------------------------------------------------------------
__global__ __launch_bounds__(256) void softmax_kernel(
    const float* __restrict__ logits, float* __restrict__ out_row,
    int* __restrict__ idx_out) {
  __shared__ float sval[256];
  __shared__ int sidx[256];
  const int tid = threadIdx.x;
  float best = -INFINITY; int bidx = 0x7fffffff;
  for (int i = tid; i < OUT_SZ; i += 256) {
    float v = logits[i];
    if (v > best) { best = v; bidx = i; }   // strided i ascending -> first max kept
  }
  sval[tid] = best; sidx[tid] = bidx;
  __syncthreads();
  for (int s = 128; s > 0; s >>= 1) {
    if (tid < s) {
      float v2 = sval[tid + s]; int i2 = sidx[tid + s];
      if (v2 > sval[tid] || (v2 == sval[tid] && i2 < sidx[tid])) {
        sval[tid] = v2; sidx[tid] = i2;
      }
    }
    __syncthreads();
  }
  const float m = sval[0];
  const int amax = sidx[0];
  __syncthreads();
  float lsum = 0.f;
  for (int i = tid; i < OUT_SZ; i += 256) lsum += expf(logits[i] - m);
  sval[tid] = lsum;
  __syncthreads();
  for (int s = 128; s > 0; s >>= 1) {
    if (tid < s) sval[tid] += sval[tid + s];
    __syncthreads();
  }
  const float ls = logf(sval[0]);
  for (int i = tid; i < OUT_SZ; i += 256) out_row[i] = logits[i] - m - ls;
  if (tid == 0) *idx_out = amax;
}

// ---------------------------------------------------------------------------
extern "C" void kernel_launch(void* const* d_in, const int* in_sizes, int n_in,
                              void* d_out, int out_size, void* d_ws, size_t ws_size,
                              hipStream_t stream) {
  const float* input   = (const float*)d_in[0];
  const float* enc_Wih = (const float*)d_in[1];
  const float* enc_Whh = (const float*)d_in[2];
  const float* enc_bih = (const float*)d_in[3];
  const float* enc_bhh = (const float*)d_in[4];
  const float* dec_Wih = (const float*)d_in[5];
  const float* dec_Whh = (const float*)d_in[6];
  const float* dec_bih = (const float*)d_in[7];
  const float* dec_bhh = (const float*)d_in[8];
  const float* W_out   = (const float*)d_in[9];
  const float* b_out   = (const float*)d_in[10];
  float* out = (float*)d_out;

  float* ws = (float*)d_ws;
  float* Gi     = ws;                                   // 512*6144
  float* ha     = ws + (size_t)SEQ_LEN * G3;            // 2048
  float* hb     = ha + HID;                             // 2048
  float* logits = hb + HID;                             // 4096
  int*   idxp   = (int*)(logits + OUT_SZ);              // 1

  hipMemsetAsync(ha, 0, HID * sizeof(float), stream);   // h0 = 0

  dim3 g0(SEQ_LEN / BM, G3 / BN);
  gemm_gi<<<g0, 256, 0, stream>>>(input, enc_Wih, enc_bih, Gi);

  float* hin = ha; float* hout = hb;
  for (int t = 0; t < SEQ_LEN; t++) {
    enc_step<<<HID / 4, 256, 0, stream>>>(Gi + (size_t)t * G3, hin, enc_Whh,
                                          enc_bhh, hout);
    float* tmp = hin; hin = hout; hout = tmp;
  }
  // h_enc now in hin
  for (int s = 0; s < STEPS; s++) {
    dec_step<<<HID / 4, 256, 0, stream>>>(dec_Wih, dec_bih, idxp, s == 0 ? 0 : 1,
                                          hin, dec_Whh, dec_bhh, hout);
    logits_kernel<<<OUT_SZ / 4, 256, 0, stream>>>(W_out, b_out, hout, logits);
    softmax_kernel<<<1, 256, 0, stream>>>(logits, out + (size_t)s * OUT_SZ, idxp);
    float* tmp = hin; hin = hout; hout = tmp;
  }
}